// Round 6
// baseline (1464.826 us; speedup 1.0000x reference)
//
#include <hip/hip_runtime.h>

// EdgeClassifierGNN: 3x SAGEConv(mean) + edge MLP on MI355X.
// R5 (resubmit after broker timeout): fix R2's occupancy collapse (VGPR=172
// from compiler hoisting the unrolled per-lane weight-column loads). Weights
// now staged in LDS (32 KB/block), 4 nodes per wave to amortize LDS reads;
// precomp un-fused from layer 3 (occupancy > fusion for latency-bound gathers).

__global__ __launch_bounds__(256) void hist_kernel(const int* __restrict__ ei, int E,
                                                   int* __restrict__ cnt) {
    int e = blockIdx.x * blockDim.x + threadIdx.x;
    if (e < E) atomicAdd(&cnt[ei[E + e]], 1);
}

__global__ __launch_bounds__(1024) void scan_kernel(const int* __restrict__ cnt,
                                                    int* __restrict__ rowptr, int N) {
    __shared__ int sums[1024];
    int t = threadIdx.x;
    int chunk = (N + 1023) >> 10;
    int start = t * chunk;
    int end = min(start + chunk, N);
    int s = 0;
    for (int i = start; i < end; ++i) s += cnt[i];
    sums[t] = s;
    __syncthreads();
    for (int off = 1; off < 1024; off <<= 1) {
        int v = (t >= off) ? sums[t - off] : 0;
        __syncthreads();
        sums[t] += v;
        __syncthreads();
    }
    int run = (t == 0) ? 0 : sums[t - 1];
    if (t == 0) rowptr[0] = 0;
    for (int i = start; i < end; ++i) { run += cnt[i]; rowptr[i + 1] = run; }
}

__global__ __launch_bounds__(256) void fill_kernel(const int* __restrict__ ei, int E,
                                                   const int* __restrict__ rowptr,
                                                   int* __restrict__ cursor,
                                                   int2* __restrict__ ce) {
    int e = blockIdx.x * blockDim.x + threadIdx.x;
    if (e >= E) return;
    int s = ei[e], d = ei[E + e];
    int p = rowptr[d] + atomicAdd(&cursor[d], 1);
    ce[p] = make_int2(s, e);
}

// SAGE layer 1: 16 -> 64. One wave per node; 4 sub-groups of 16 lanes each
// gather one neighbor row (64B). Weight arrays small (16 rows) -> registers ok.
__global__ __launch_bounds__(256) void sage16_kernel(
        const float* __restrict__ x, const int* __restrict__ rowptr,
        const int2* __restrict__ ce, const float* __restrict__ Wl,
        const float* __restrict__ Wr, const float* __restrict__ b,
        float* __restrict__ out, int N) {
    int lane = threadIdx.x & 63;
    int wid  = (blockIdx.x * blockDim.x + threadIdx.x) >> 6;
    int nwv  = (gridDim.x * blockDim.x) >> 6;
    int f = lane & 15, g = lane >> 4;
    for (int i = wid; i < N; i += nwv) {
        int s0 = rowptr[i], s1 = rowptr[i + 1];
        float acc0 = 0.f, acc1 = 0.f;
        int j = s0 + g;
        for (; j + 4 < s1; j += 8) {
            int c0 = ce[j].x, c1 = ce[j + 4].x;
            acc0 += x[(size_t)c0 * 16 + f];
            acc1 += x[(size_t)c1 * 16 + f];
        }
        if (j < s1) acc0 += x[(size_t)ce[j].x * 16 + f];
        float acc = acc0 + acc1;
        acc += __shfl_xor(acc, 16);
        acc += __shfl_xor(acc, 32);
        float inv  = 1.0f / fmaxf((float)(s1 - s0), 1.0f);
        float mean = acc * inv;              // lane l holds mean[l&15]
        float xi   = x[(size_t)i * 16 + f];  // lane l holds x[i][l&15]
        float o = b[lane];
        #pragma unroll
        for (int ff = 0; ff < 16; ++ff) {
            float m  = __shfl(mean, ff);
            float xv = __shfl(xi, ff);
            o += m * Wl[ff * 64 + lane];
            o += xv * Wr[ff * 64 + lane];
        }
        out[(size_t)i * 64 + lane] = fmaxf(o, 0.f);
    }
}

// SAGE layer 64 -> 64. Weights in LDS (32 KB), 4 nodes per wave.
__global__ __launch_bounds__(256) void sage64_kernel(
        const float* __restrict__ hin, const int* __restrict__ rowptr,
        const int2* __restrict__ ce, const float* __restrict__ Wl,
        const float* __restrict__ Wr, const float* __restrict__ b,
        float* __restrict__ out, int N) {
    __shared__ float WlL[64 * 64];
    __shared__ float WrL[64 * 64];
    int t = threadIdx.x;
    for (int k = t; k < 1024; k += 256) {
        ((float4*)WlL)[k] = ((const float4*)Wl)[k];
        ((float4*)WrL)[k] = ((const float4*)Wr)[k];
    }
    __syncthreads();
    int lane = t & 63;
    int wid  = (blockIdx.x * blockDim.x + t) >> 6;
    int nwv  = (gridDim.x * blockDim.x) >> 6;
    float bias = b[lane];
    for (int i0 = wid * 4; i0 < N; i0 += nwv * 4) {
        float m0 = 0.f, m1 = 0.f, m2 = 0.f, m3 = 0.f;
        float h0 = 0.f, h1 = 0.f, h2 = 0.f, h3 = 0.f;
        #pragma unroll
        for (int n = 0; n < 4; ++n) {
            int i = i0 + n;
            float m = 0.f, h = 0.f;
            if (i < N) {
                int s0 = rowptr[i], s1 = rowptr[i + 1];
                float a0 = 0.f, a1 = 0.f, a2 = 0.f, a3 = 0.f;
                int j = s0;
                for (; j + 4 <= s1; j += 4) {
                    int c0 = ce[j].x, c1 = ce[j + 1].x;
                    int c2 = ce[j + 2].x, c3 = ce[j + 3].x;
                    a0 += hin[(size_t)c0 * 64 + lane];
                    a1 += hin[(size_t)c1 * 64 + lane];
                    a2 += hin[(size_t)c2 * 64 + lane];
                    a3 += hin[(size_t)c3 * 64 + lane];
                }
                for (; j < s1; ++j) a0 += hin[(size_t)ce[j].x * 64 + lane];
                m = ((a0 + a1) + (a2 + a3)) / fmaxf((float)(s1 - s0), 1.0f);
                h = hin[(size_t)i * 64 + lane];
            }
            if (n == 0) { m0 = m; h0 = h; }
            else if (n == 1) { m1 = m; h1 = h; }
            else if (n == 2) { m2 = m; h2 = h; }
            else { m3 = m; h3 = h; }
        }
        float o0 = bias, o1 = bias, o2 = bias, o3 = bias;
        #pragma unroll
        for (int ff = 0; ff < 64; ++ff) {
            float wl = WlL[ff * 64 + lane];
            float wr = WrL[ff * 64 + lane];
            o0 += __shfl(m0, ff) * wl + __shfl(h0, ff) * wr;
            o1 += __shfl(m1, ff) * wl + __shfl(h1, ff) * wr;
            o2 += __shfl(m2, ff) * wl + __shfl(h2, ff) * wr;
            o3 += __shfl(m3, ff) * wl + __shfl(h3, ff) * wr;
        }
        if (i0 < N)     out[(size_t)i0 * 64 + lane]       = fmaxf(o0, 0.f);
        if (i0 + 1 < N) out[(size_t)(i0 + 1) * 64 + lane] = fmaxf(o1, 0.f);
        if (i0 + 2 < N) out[(size_t)(i0 + 2) * 64 + lane] = fmaxf(o2, 0.f);
        if (i0 + 3 < N) out[(size_t)(i0 + 3) * 64 + lane] = fmaxf(o3, 0.f);
    }
}

// Edge-MLP precompute: A[i] = h3[i]@Wm1[0:64] + bm1 ; B[i] = h3[i]@Wm1[64:128].
// Weights in LDS, 4 nodes per wave, pure streaming.
__global__ __launch_bounds__(256) void precomp_kernel(
        const float* __restrict__ h3, const float* __restrict__ Wm1,
        const float* __restrict__ bm1, float* __restrict__ A,
        float* __restrict__ Bf, int N) {
    __shared__ float WaL[64 * 64];
    __shared__ float WbL[64 * 64];
    int t = threadIdx.x;
    for (int k = t; k < 1024; k += 256) {
        ((float4*)WaL)[k] = ((const float4*)Wm1)[k];
        ((float4*)WbL)[k] = ((const float4*)Wm1)[1024 + k];
    }
    __syncthreads();
    int lane = t & 63;
    int wid  = (blockIdx.x * blockDim.x + t) >> 6;
    int nwv  = (gridDim.x * blockDim.x) >> 6;
    float bias = bm1[lane];
    for (int i0 = wid * 4; i0 < N; i0 += nwv * 4) {
        float h0 = 0.f, h1 = 0.f, h2 = 0.f, h3v = 0.f;
        if (i0 < N)     h0  = h3[(size_t)i0 * 64 + lane];
        if (i0 + 1 < N) h1  = h3[(size_t)(i0 + 1) * 64 + lane];
        if (i0 + 2 < N) h2  = h3[(size_t)(i0 + 2) * 64 + lane];
        if (i0 + 3 < N) h3v = h3[(size_t)(i0 + 3) * 64 + lane];
        float a0 = bias, a1 = bias, a2 = bias, a3 = bias;
        float b0 = 0.f, b1 = 0.f, b2 = 0.f, b3 = 0.f;
        #pragma unroll
        for (int ff = 0; ff < 64; ++ff) {
            float wa = WaL[ff * 64 + lane];
            float wb = WbL[ff * 64 + lane];
            float v0 = __shfl(h0, ff), v1 = __shfl(h1, ff);
            float v2 = __shfl(h2, ff), v3 = __shfl(h3v, ff);
            a0 += v0 * wa; b0 += v0 * wb;
            a1 += v1 * wa; b1 += v1 * wb;
            a2 += v2 * wa; b2 += v2 * wb;
            a3 += v3 * wa; b3 += v3 * wb;
        }
        if (i0 < N)     { A[(size_t)i0 * 64 + lane] = a0;       Bf[(size_t)i0 * 64 + lane] = b0; }
        if (i0 + 1 < N) { A[(size_t)(i0 + 1) * 64 + lane] = a1; Bf[(size_t)(i0 + 1) * 64 + lane] = b1; }
        if (i0 + 2 < N) { A[(size_t)(i0 + 2) * 64 + lane] = a2; Bf[(size_t)(i0 + 2) * 64 + lane] = b2; }
        if (i0 + 3 < N) { A[(size_t)(i0 + 3) * 64 + lane] = a3; Bf[(size_t)(i0 + 3) * 64 + lane] = b3; }
    }
}

// Edge MLP, dst-grouped: one wave per dst node, B[d] read once (sequential),
// only A[src] + attr gathered. Two edges per iteration for ILP.
__global__ __launch_bounds__(256) void edge_kernel(
        const float* __restrict__ A, const float* __restrict__ Bf,
        const int* __restrict__ rowptr, const int2* __restrict__ ce,
        const float* __restrict__ attr,
        const float* __restrict__ Wm1, const float* __restrict__ Wm2,
        const float* __restrict__ Wm3, const float* __restrict__ bm2,
        const float* __restrict__ bm3, float* __restrict__ out, int N) {
    int lane = threadIdx.x & 63;
    int wid  = (blockIdx.x * blockDim.x + threadIdx.x) >> 6;
    int nwv  = (gridDim.x * blockDim.x) >> 6;
    int p = lane & 31;
    int obase = lane & 32;          // this half reduces z1[obase..obase+31]
    float wmE[8];
    #pragma unroll
    for (int k = 0; k < 8; ++k) wmE[k] = Wm1[(128 + k) * 64 + lane];
    float wm2[32];
    #pragma unroll
    for (int k = 0; k < 32; ++k) wm2[k] = Wm2[(obase + k) * 32 + p];
    float w3    = Wm3[p];
    float bias2 = bm2[p];
    float bias3 = bm3[0];

    for (int d = wid; d < N; d += nwv) {
        int s0 = rowptr[d], s1 = rowptr[d + 1];
        if (s0 == s1) continue;
        float Bd = Bf[(size_t)d * 64 + lane];
        int j = s0;
        for (; j + 2 <= s1; j += 2) {
            int2 ce0 = ce[j], ce1 = ce[j + 1];
            float a0 = A[(size_t)ce0.x * 64 + lane];
            float a1 = A[(size_t)ce1.x * 64 + lane];
            int eid  = (lane & 8) ? ce1.y : ce0.y;
            float av = (lane < 16) ? attr[(size_t)eid * 8 + (lane & 7)] : 0.f;
            float z0 = Bd + a0, z1 = Bd + a1;
            #pragma unroll
            for (int k = 0; k < 8; ++k) {
                z0 += __shfl(av, k)     * wmE[k];
                z1 += __shfl(av, 8 + k) * wmE[k];
            }
            z0 = fmaxf(z0, 0.f); z1 = fmaxf(z1, 0.f);
            float y0 = 0.f, y1 = 0.f;
            #pragma unroll
            for (int k = 0; k < 32; ++k) {
                y0 += __shfl(z0, obase + k) * wm2[k];
                y1 += __shfl(z1, obase + k) * wm2[k];
            }
            y0 += __shfl_xor(y0, 32);
            y1 += __shfl_xor(y1, 32);
            y0 = fmaxf(y0 + bias2, 0.f) * w3;
            y1 = fmaxf(y1 + bias2, 0.f) * w3;
            float t = (lane < 32) ? y0 : y1;   // half0 -> edge0, half1 -> edge1
            t += __shfl_xor(t, 16);
            t += __shfl_xor(t, 8);
            t += __shfl_xor(t, 4);
            t += __shfl_xor(t, 2);
            t += __shfl_xor(t, 1);
            if (lane == 0)       out[ce0.y] = t + bias3;
            else if (lane == 32) out[ce1.y] = t + bias3;
        }
        if (j < s1) {  // tail edge
            int2 ce0 = ce[j];
            float a0 = A[(size_t)ce0.x * 64 + lane];
            float av = (lane < 8) ? attr[(size_t)ce0.y * 8 + lane] : 0.f;
            float z0 = Bd + a0;
            #pragma unroll
            for (int k = 0; k < 8; ++k) z0 += __shfl(av, k) * wmE[k];
            z0 = fmaxf(z0, 0.f);
            float y0 = 0.f;
            #pragma unroll
            for (int k = 0; k < 32; ++k) y0 += __shfl(z0, obase + k) * wm2[k];
            y0 += __shfl_xor(y0, 32);
            y0 = fmaxf(y0 + bias2, 0.f) * w3;
            float t = (lane < 32) ? y0 : 0.f;
            t += __shfl_xor(t, 16);
            t += __shfl_xor(t, 8);
            t += __shfl_xor(t, 4);
            t += __shfl_xor(t, 2);
            t += __shfl_xor(t, 1);
            if (lane == 0) out[ce0.y] = t + bias3;
        }
    }
}

extern "C" void kernel_launch(void* const* d_in, const int* in_sizes, int n_in,
                              void* d_out, int out_size, void* d_ws, size_t ws_size,
                              hipStream_t stream) {
    const float* x    = (const float*)d_in[0];
    const int*   ei   = (const int*)d_in[1];
    const float* attr = (const float*)d_in[2];
    const float* W1l  = (const float*)d_in[3];
    const float* W1r  = (const float*)d_in[4];
    const float* b1   = (const float*)d_in[5];
    const float* W2l  = (const float*)d_in[6];
    const float* W2r  = (const float*)d_in[7];
    const float* b2   = (const float*)d_in[8];
    const float* W3l  = (const float*)d_in[9];
    const float* W3r  = (const float*)d_in[10];
    const float* b3   = (const float*)d_in[11];
    const float* Wm1  = (const float*)d_in[12];
    const float* bm1  = (const float*)d_in[13];
    const float* Wm2  = (const float*)d_in[14];
    const float* bm2  = (const float*)d_in[15];
    const float* Wm3  = (const float*)d_in[16];
    const float* bm3  = (const float*)d_in[17];
    float* out = (float*)d_out;

    const int N = in_sizes[0] / 16;
    const int E = in_sizes[1] / 2;

    // Workspace layout
    char* ws = (char*)d_ws;
    size_t off = 0;
    int* cnt    = (int*)(ws + off); off += (size_t)N * 4;
    int* cursor = (int*)(ws + off); off += (size_t)N * 4;
    int* rowptr = (int*)(ws + off); off += (size_t)(N + 1) * 4;
    off = (off + 255) & ~(size_t)255;
    int2* ce    = (int2*)(ws + off); off += (size_t)E * 8;
    off = (off + 255) & ~(size_t)255;
    float* buf0 = (float*)(ws + off); off += (size_t)N * 64 * 4;  // h1
    float* buf1 = (float*)(ws + off); off += (size_t)N * 64 * 4;  // h2
    float* buf2 = (float*)(ws + off); off += (size_t)N * 64 * 4;  // h3, later B
    float* buf3 = (float*)(ws + off); off += (size_t)N * 64 * 4;  // A

    hipMemsetAsync(ws, 0, (size_t)N * 8, stream);  // cnt + cursor

    const int TB = 256;
    int ebBlocks = (E + TB - 1) / TB;
    int nwBlocks = (N * 64 + TB - 1) / TB;           // one wave per node
    int n4Blocks = (N + 4 * 4 - 1) / (4 * 4);        // 4 nodes/wave, 4 waves/block

    hist_kernel<<<ebBlocks, TB, 0, stream>>>(ei, E, cnt);
    scan_kernel<<<1, 1024, 0, stream>>>(cnt, rowptr, N);
    fill_kernel<<<ebBlocks, TB, 0, stream>>>(ei, E, rowptr, cursor, ce);

    sage16_kernel<<<nwBlocks, TB, 0, stream>>>(x, rowptr, ce, W1l, W1r, b1, buf0, N);
    sage64_kernel<<<n4Blocks, TB, 0, stream>>>(buf0, rowptr, ce, W2l, W2r, b2, buf1, N);
    sage64_kernel<<<n4Blocks, TB, 0, stream>>>(buf1, rowptr, ce, W3l, W3r, b3, buf2, N);

    precomp_kernel<<<n4Blocks, TB, 0, stream>>>(buf2, Wm1, bm1, buf3, buf2, N);

    edge_kernel<<<nwBlocks, TB, 0, stream>>>(buf3, buf2, rowptr, ce, attr,
                                             Wm1, Wm2, Wm3, bm2, bm3, out, N);
}

// Round 11
// 815.169 us; speedup vs baseline: 1.7970x; 1.7970x over previous
//
#include <hip/hip_runtime.h>

// EdgeClassifierGNN R10 (resubmit after broker timeout) = R7 + correctness
// fix: edge_kernel attr must be indexed by ORIGINAL edge id (eid[e]), not
// CSR slot position (R9 fail, absmax 0.1 = permuted attrs). Structure
// unchanged: lane-local matvec reductions via LDS transpose tiles +
// wave-uniform scalar weight loads; sage64 split into gather_mean +
// linear64; layer3 fused with A/B precompute.

__global__ __launch_bounds__(256) void hist_kernel(const int* __restrict__ ei, int E,
                                                   int* __restrict__ cnt) {
    int e = blockIdx.x * blockDim.x + threadIdx.x;
    if (e < E) atomicAdd(&cnt[ei[E + e]], 1);
}

__global__ __launch_bounds__(1024) void scan_kernel(const int* __restrict__ cnt,
                                                    int* __restrict__ rowptr, int N) {
    __shared__ int sums[1024];
    int t = threadIdx.x;
    int chunk = (N + 1023) >> 10;
    int start = t * chunk;
    int end = min(start + chunk, N);
    int s = 0;
    for (int i = start; i < end; ++i) s += cnt[i];
    sums[t] = s;
    __syncthreads();
    for (int off = 1; off < 1024; off <<= 1) {
        int v = (t >= off) ? sums[t - off] : 0;
        __syncthreads();
        sums[t] += v;
        __syncthreads();
    }
    int run = (t == 0) ? 0 : sums[t - 1];
    if (t == 0) rowptr[0] = 0;
    for (int i = start; i < end; ++i) { run += cnt[i]; rowptr[i + 1] = run; }
}

// CSR fill: sd[p]=(src,dst) for scalar loads, eid[p] separate for coalesced.
__global__ __launch_bounds__(256) void fill_kernel(const int* __restrict__ ei, int E,
                                                   const int* __restrict__ rowptr,
                                                   int* __restrict__ cursor,
                                                   int2* __restrict__ sd,
                                                   int* __restrict__ eid) {
    int e = blockIdx.x * blockDim.x + threadIdx.x;
    if (e >= E) return;
    int s = ei[e], d = ei[E + e];
    int p = rowptr[d] + atomicAdd(&cursor[d], 1);
    sd[p] = make_int2(s, d);
    eid[p] = e;
}

// SAGE layer 1: 16 -> 64. One wave per node; 4 groups of 16 lanes gather rows.
__global__ __launch_bounds__(256) void sage16_kernel(
        const float* __restrict__ x, const int* __restrict__ rowptr,
        const int2* __restrict__ sd, const float* __restrict__ Wl,
        const float* __restrict__ Wr, const float* __restrict__ b,
        float* __restrict__ out, int N) {
    int lane = threadIdx.x & 63;
    int wid  = (blockIdx.x * blockDim.x + threadIdx.x) >> 6;
    if (wid >= N) return;
    int f = lane & 15, g = lane >> 4;
    int s0 = rowptr[wid], s1 = rowptr[wid + 1];
    float acc0 = 0.f, acc1 = 0.f;
    int j = s0 + g;
    for (; j + 4 < s1; j += 8) {
        int c0 = sd[j].x, c1 = sd[j + 4].x;
        acc0 += x[(size_t)c0 * 16 + f];
        acc1 += x[(size_t)c1 * 16 + f];
    }
    if (j < s1) acc0 += x[(size_t)sd[j].x * 16 + f];
    float acc = acc0 + acc1;
    acc += __shfl_xor(acc, 16);
    acc += __shfl_xor(acc, 32);
    float inv  = 1.0f / fmaxf((float)(s1 - s0), 1.0f);
    float mean = acc * inv;                 // lane l holds mean[l&15]
    float xi   = x[(size_t)wid * 16 + f];   // lane l holds x[i][l&15]
    float o = b[lane];
    #pragma unroll
    for (int ff = 0; ff < 16; ++ff) {
        float m  = __shfl(mean, ff);
        float xv = __shfl(xi, ff);
        o += m * Wl[ff * 64 + lane];
        o += xv * Wr[ff * 64 + lane];
    }
    out[(size_t)wid * 64 + lane] = fmaxf(o, 0.f);
}

// Mean aggregation 64-wide: one wave per node, 8 rows in flight, zero DS.
__global__ __launch_bounds__(256) void gather_mean_kernel(
        const float* __restrict__ hin, const int* __restrict__ rowptr,
        const int2* __restrict__ sd, float* __restrict__ m, int N) {
    int lane = threadIdx.x & 63;
    int wid  = (blockIdx.x * blockDim.x + threadIdx.x) >> 6;
    if (wid >= N) return;
    int s0 = rowptr[wid], s1 = rowptr[wid + 1];
    float a0 = 0.f, a1 = 0.f, a2 = 0.f, a3 = 0.f;
    float a4 = 0.f, a5 = 0.f, a6 = 0.f, a7 = 0.f;
    int j = s0;
    for (; j + 8 <= s1; j += 8) {
        int c0 = sd[j].x,     c1 = sd[j + 1].x, c2 = sd[j + 2].x, c3 = sd[j + 3].x;
        int c4 = sd[j + 4].x, c5 = sd[j + 5].x, c6 = sd[j + 6].x, c7 = sd[j + 7].x;
        a0 += hin[(size_t)c0 * 64 + lane];
        a1 += hin[(size_t)c1 * 64 + lane];
        a2 += hin[(size_t)c2 * 64 + lane];
        a3 += hin[(size_t)c3 * 64 + lane];
        a4 += hin[(size_t)c4 * 64 + lane];
        a5 += hin[(size_t)c5 * 64 + lane];
        a6 += hin[(size_t)c6 * 64 + lane];
        a7 += hin[(size_t)c7 * 64 + lane];
    }
    for (; j < s1; ++j) a0 += hin[(size_t)sd[j].x * 64 + lane];
    float s = ((a0 + a1) + (a2 + a3)) + ((a4 + a5) + (a6 + a7));
    m[(size_t)wid * 64 + lane] = s / fmaxf((float)(s1 - s0), 1.0f);
}

// out[i] = relu(m[i] @ Wl + h[i] @ Wr + b). One wave per 64 nodes.
// Phase1: coalesced load -> LDS transpose. Phase2: lane=node, lane-local
// FMAs with wave-uniform (scalar) weight loads. Phase3: transpose back.
__global__ __launch_bounds__(64) void linear64_kernel(
        const float* __restrict__ m, const float* __restrict__ h,
        const float* __restrict__ Wl, const float* __restrict__ Wr,
        const float* __restrict__ b, float* __restrict__ out, int N) {
    __shared__ float tile[64 * 132];     // [node][mean(64)|h(64)], stride 132
    int lane = threadIdx.x;
    int base = blockIdx.x * 64;
    for (int n = 0; n < 64; ++n) {
        int i = base + n;
        float mv = 0.f, hv = 0.f;
        if (i < N) { mv = m[(size_t)i * 64 + lane]; hv = h[(size_t)i * 64 + lane]; }
        tile[n * 132 + lane]      = mv;
        tile[n * 132 + 64 + lane] = hv;
    }
    __syncthreads();
    float y[64];
    #pragma unroll
    for (int c = 0; c < 64; ++c) y[c] = b[c];
    for (int it = 0; it < 16; ++it) {     // mean chunks
        float4 z = *(const float4*)&tile[lane * 132 + it * 4];
        #pragma unroll
        for (int q = 0; q < 4; ++q) {
            float zv = q == 0 ? z.x : q == 1 ? z.y : q == 2 ? z.z : z.w;
            int ff = it * 4 + q;
            #pragma unroll
            for (int c = 0; c < 64; ++c) y[c] += zv * Wl[ff * 64 + c];
        }
    }
    for (int it = 0; it < 16; ++it) {     // h chunks
        float4 z = *(const float4*)&tile[lane * 132 + 64 + it * 4];
        #pragma unroll
        for (int q = 0; q < 4; ++q) {
            float zv = q == 0 ? z.x : q == 1 ? z.y : q == 2 ? z.z : z.w;
            int ff = it * 4 + q;
            #pragma unroll
            for (int c = 0; c < 64; ++c) y[c] += zv * Wr[ff * 64 + c];
        }
    }
    __syncthreads();
    #pragma unroll
    for (int c = 0; c < 64; ++c) tile[lane * 65 + c] = fmaxf(y[c], 0.f);
    __syncthreads();
    for (int n = 0; n < 64; ++n) {
        int i = base + n;
        if (i < N) out[(size_t)i * 64 + lane] = tile[n * 65 + lane];
    }
}

// Layer-3 linear fused with edge-MLP precompute:
// h3 = relu(m@W3l + h2@W3r + b3) kept in registers (lane=node), then
// A = h3@Wm1[0:64]+bm1, B = h3@Wm1[64:128], transposed out via LDS.
__global__ __launch_bounds__(64) void linear64_ab_kernel(
        const float* __restrict__ m, const float* __restrict__ h,
        const float* __restrict__ Wl, const float* __restrict__ Wr,
        const float* __restrict__ b, const float* __restrict__ Wm1,
        const float* __restrict__ bm1, float* __restrict__ A,
        float* __restrict__ Bf, int N) {
    __shared__ float tile[64 * 132];
    int lane = threadIdx.x;
    int base = blockIdx.x * 64;
    for (int n = 0; n < 64; ++n) {
        int i = base + n;
        float mv = 0.f, hv = 0.f;
        if (i < N) { mv = m[(size_t)i * 64 + lane]; hv = h[(size_t)i * 64 + lane]; }
        tile[n * 132 + lane]      = mv;
        tile[n * 132 + 64 + lane] = hv;
    }
    __syncthreads();
    float h3[64];
    #pragma unroll
    for (int c = 0; c < 64; ++c) h3[c] = b[c];
    for (int it = 0; it < 16; ++it) {
        float4 z = *(const float4*)&tile[lane * 132 + it * 4];
        #pragma unroll
        for (int q = 0; q < 4; ++q) {
            float zv = q == 0 ? z.x : q == 1 ? z.y : q == 2 ? z.z : z.w;
            int ff = it * 4 + q;
            #pragma unroll
            for (int c = 0; c < 64; ++c) h3[c] += zv * Wl[ff * 64 + c];
        }
    }
    for (int it = 0; it < 16; ++it) {
        float4 z = *(const float4*)&tile[lane * 132 + 64 + it * 4];
        #pragma unroll
        for (int q = 0; q < 4; ++q) {
            float zv = q == 0 ? z.x : q == 1 ? z.y : q == 2 ? z.z : z.w;
            int ff = it * 4 + q;
            #pragma unroll
            for (int c = 0; c < 64; ++c) h3[c] += zv * Wr[ff * 64 + c];
        }
    }
    #pragma unroll
    for (int c = 0; c < 64; ++c) h3[c] = fmaxf(h3[c], 0.f);
    // A = h3 @ Wm1[0:64] + bm1
    {
        float yA[64];
        #pragma unroll
        for (int c = 0; c < 64; ++c) yA[c] = bm1[c];
        #pragma unroll
        for (int ff = 0; ff < 64; ++ff) {
            float zv = h3[ff];
            #pragma unroll
            for (int c = 0; c < 64; ++c) yA[c] += zv * Wm1[ff * 64 + c];
        }
        __syncthreads();
        #pragma unroll
        for (int c = 0; c < 64; ++c) tile[lane * 65 + c] = yA[c];
        __syncthreads();
        for (int n = 0; n < 64; ++n) {
            int i = base + n;
            if (i < N) A[(size_t)i * 64 + lane] = tile[n * 65 + lane];
        }
    }
    // B = h3 @ Wm1[64:128]
    {
        float yB[64];
        #pragma unroll
        for (int c = 0; c < 64; ++c) yB[c] = 0.f;
        #pragma unroll
        for (int ff = 0; ff < 64; ++ff) {
            float zv = h3[ff];
            #pragma unroll
            for (int c = 0; c < 64; ++c) yB[c] += zv * Wm1[(64 + ff) * 64 + c];
        }
        __syncthreads();
        #pragma unroll
        for (int c = 0; c < 64; ++c) tile[lane * 65 + c] = yB[c];
        __syncthreads();
        for (int n = 0; n < 64; ++n) {
            int i = base + n;
            if (i < N) Bf[(size_t)i * 64 + lane] = tile[n * 65 + lane];
        }
    }
}

// Edge MLP: one wave per 64 edges (CSR order -> dst-local for cache).
// Phase1 (lane=channel): z1 = relu(A[src]+B[dst]+attr[eid]@WmE) -> LDS rows.
// Phase2 (lane=edge): y = relu(z@Wm2+bm2) lane-local with scalar weights,
// logit = y@Wm3+bm3, scatter to out[eid].
__global__ __launch_bounds__(64) void edge_kernel(
        const float* __restrict__ A, const float* __restrict__ Bf,
        const int2* __restrict__ sd, const int* __restrict__ eid,
        const float* __restrict__ attr,
        const float* __restrict__ Wm1, const float* __restrict__ Wm2,
        const float* __restrict__ bm2, const float* __restrict__ Wm3,
        const float* __restrict__ bm3, float* __restrict__ out, int E) {
    __shared__ float zt[64 * 68];
    int lane = threadIdx.x;
    int base = blockIdx.x * 64;
    float wmE[8];
    #pragma unroll
    for (int k = 0; k < 8; ++k) wmE[k] = Wm1[(128 + k) * 64 + lane];
    #pragma unroll 4
    for (int i = 0; i < 64; i += 2) {
        int e0 = base + i, e1 = base + i + 1;
        float z0 = 0.f, z1 = 0.f;
        if (e0 < E) {
            int2 p0 = sd[e0];
            int id0 = eid[e0];                    // ORIGINAL edge id (bugfix)
            float v = A[(size_t)p0.x * 64 + lane] + Bf[(size_t)p0.y * 64 + lane];
            #pragma unroll
            for (int k = 0; k < 8; ++k) v += attr[(size_t)id0 * 8 + k] * wmE[k];
            z0 = fmaxf(v, 0.f);
        }
        if (e1 < E) {
            int2 p1 = sd[e1];
            int id1 = eid[e1];                    // ORIGINAL edge id (bugfix)
            float v = A[(size_t)p1.x * 64 + lane] + Bf[(size_t)p1.y * 64 + lane];
            #pragma unroll
            for (int k = 0; k < 8; ++k) v += attr[(size_t)id1 * 8 + k] * wmE[k];
            z1 = fmaxf(v, 0.f);
        }
        zt[i * 68 + lane]       = z0;
        zt[(i + 1) * 68 + lane] = z1;
    }
    __syncthreads();
    float y[32];
    #pragma unroll
    for (int p = 0; p < 32; ++p) y[p] = bm2[p];
    for (int it = 0; it < 16; ++it) {
        float4 z = *(const float4*)&zt[lane * 68 + it * 4];
        #pragma unroll
        for (int q = 0; q < 4; ++q) {
            float zv = q == 0 ? z.x : q == 1 ? z.y : q == 2 ? z.z : z.w;
            int o = it * 4 + q;
            #pragma unroll
            for (int p = 0; p < 32; ++p) y[p] += zv * Wm2[o * 32 + p];
        }
    }
    float logit = bm3[0];
    #pragma unroll
    for (int p = 0; p < 32; ++p) logit += fmaxf(y[p], 0.f) * Wm3[p];
    int e = base + lane;
    if (e < E) out[eid[e]] = logit;
}

extern "C" void kernel_launch(void* const* d_in, const int* in_sizes, int n_in,
                              void* d_out, int out_size, void* d_ws, size_t ws_size,
                              hipStream_t stream) {
    const float* x    = (const float*)d_in[0];
    const int*   ei   = (const int*)d_in[1];
    const float* attr = (const float*)d_in[2];
    const float* W1l  = (const float*)d_in[3];
    const float* W1r  = (const float*)d_in[4];
    const float* b1   = (const float*)d_in[5];
    const float* W2l  = (const float*)d_in[6];
    const float* W2r  = (const float*)d_in[7];
    const float* b2   = (const float*)d_in[8];
    const float* W3l  = (const float*)d_in[9];
    const float* W3r  = (const float*)d_in[10];
    const float* b3   = (const float*)d_in[11];
    const float* Wm1  = (const float*)d_in[12];
    const float* bm1  = (const float*)d_in[13];
    const float* Wm2  = (const float*)d_in[14];
    const float* bm2  = (const float*)d_in[15];
    const float* Wm3  = (const float*)d_in[16];
    const float* bm3  = (const float*)d_in[17];
    float* out = (float*)d_out;

    const int N = in_sizes[0] / 16;
    const int E = in_sizes[1] / 2;

    // Workspace layout
    char* ws = (char*)d_ws;
    size_t off = 0;
    int* cnt    = (int*)(ws + off); off += (size_t)N * 4;
    int* cursor = (int*)(ws + off); off += (size_t)N * 4;
    int* rowptr = (int*)(ws + off); off += (size_t)(N + 1) * 4;
    off = (off + 255) & ~(size_t)255;
    int2* sd    = (int2*)(ws + off); off += (size_t)E * 8;
    int* eid    = (int*)(ws + off);  off += (size_t)E * 4;
    off = (off + 255) & ~(size_t)255;
    float* h1 = (float*)(ws + off); off += (size_t)N * 64 * 4;  // h1, later A
    float* h2 = (float*)(ws + off); off += (size_t)N * 64 * 4;  // h2
    float* mb = (float*)(ws + off); off += (size_t)N * 64 * 4;  // mean scratch
    float* Bf = (float*)(ws + off); off += (size_t)N * 64 * 4;  // B

    hipMemsetAsync(ws, 0, (size_t)N * 8, stream);  // cnt + cursor

    const int TB = 256;
    int ebBlocks = (E + TB - 1) / TB;
    int nwBlocks = (N * 64 + TB - 1) / TB;        // one wave per node
    int b64Nodes = (N + 63) / 64;                 // one wave per 64 nodes
    int b64Edges = (E + 63) / 64;                 // one wave per 64 edges

    hist_kernel<<<ebBlocks, TB, 0, stream>>>(ei, E, cnt);
    scan_kernel<<<1, 1024, 0, stream>>>(cnt, rowptr, N);
    fill_kernel<<<ebBlocks, TB, 0, stream>>>(ei, E, rowptr, cursor, sd, eid);

    sage16_kernel<<<nwBlocks, TB, 0, stream>>>(x, rowptr, sd, W1l, W1r, b1, h1, N);

    gather_mean_kernel<<<nwBlocks, TB, 0, stream>>>(h1, rowptr, sd, mb, N);
    linear64_kernel<<<b64Nodes, 64, 0, stream>>>(mb, h1, W2l, W2r, b2, h2, N);

    gather_mean_kernel<<<nwBlocks, TB, 0, stream>>>(h2, rowptr, sd, mb, N);
    linear64_ab_kernel<<<b64Nodes, 64, 0, stream>>>(mb, h2, W3l, W3r, b3,
                                                    Wm1, bm1, h1, Bf, N);

    edge_kernel<<<b64Edges, 64, 0, stream>>>(h1, Bf, sd, eid, attr,
                                             Wm1, Wm2, bm2, Wm3, bm3, out, E);
}